// Round 2
// baseline (731.863 us; speedup 1.0000x reference)
//
#include <hip/hip_runtime.h>
#include <math.h>

// GatingFunc: logits = x @ W^T + b; top-2 -> softmax -> scatter to [N, E].
// N=131072, D=1024, E=64, K=2 (fp32 in/out).
//
// Round 5: occupancy fix. Round 4 (MFMA split-bf16 rewrite) measured ~240 us
// for the gating dispatch (total 731 = ~490 us harness fill/reset floor).
// HBM floor is ~90 us; compute aggregate ~20 us -> latency-bound at
// 2 waves/SIMD. This round: 32 tokens/wave (acc 64->32 VGPR), ~115 VGPR
// total -> __launch_bounds__(256,4) -> 4 waves/SIMD; grid 1024 blocks =
// 4096 waves = exact full residency (256 CU x 16 waves).
//  - wave = 32 tokens x 64 experts, mfma_f32_16x16x32_bf16, 3-pass split
//    bf16 (xh*wh + xh*wl + xl*wh ~= fp32; logit err ~1e-5).
//    C/D: col=lane&15 (token), row=(lane>>4)*4+reg (expert)  [HW-verified].
//  - W pre-packed by wprep into per-lane fragment order, bf16 hi/lo in d_ws
//    (256 KB, L2-resident; harness ws poison fill is unconditional, so the
//    ws path costs nothing extra). Coalesced dwordx4 frag loads.
//  - x loaded directly in fragment layout (each token row-chunk of 128 B is
//    fully consumed -> no overfetch), converted hi/lo in-register,
//    double-buffered one K-step ahead. W single-buffered: its vmcnt wait
//    retires before the younger x loads, leaving them in flight.
//  - epilogue: per-token local top-2 scan + 2 shfl_xor merges; 2 KB LDS
//    redistributes (i1,i2,g1,g2) for coalesced f32x4 writes (4 consecutive
//    rows per store instruction = 1 KB contiguous).

#define D_MODEL 1024
#define N_EXP   64
#define NSTEP   32          // K-steps of 32 (MFMA K)
#define BLOCK   256
#define TOK_PER_WAVE  32
#define TOK_PER_BLOCK 128
#define NTILE   2           // 16-token C tiles per wave

typedef float  f32x4 __attribute__((ext_vector_type(4)));
typedef __bf16 bf16x8 __attribute__((ext_vector_type(8)));

// ---- prep: pack W [64][1024] fp32 -> bf16 hi/lo A-fragments ----
// chunk c = (s*4 + g)*64 + l holds W[e = g*16 + (l&15)][k = s*32 + (l>>4)*8 .. +7]
__global__ __launch_bounds__(256) void wprep_kernel(
    const float* __restrict__ W, __bf16* __restrict__ WH, __bf16* __restrict__ WL)
{
    const int tid = blockIdx.x * 256 + threadIdx.x;   // 0..8191
    const int s = tid >> 8;
    const int g = (tid >> 6) & 3;
    const int l = tid & 63;
    const int e  = g * 16 + (l & 15);
    const int k0 = s * 32 + ((l >> 4) & 3) * 8;
    const float* __restrict__ src = W + (size_t)e * D_MODEL + k0;
    bf16x8 h, lo;
#pragma unroll
    for (int i = 0; i < 8; ++i) {
        const float f = src[i];
        const __bf16 hh = (__bf16)f;
        h[i]  = hh;
        lo[i] = (__bf16)(f - (float)hh);
    }
    reinterpret_cast<bf16x8*>(WH)[tid] = h;
    reinterpret_cast<bf16x8*>(WL)[tid] = lo;
}

__global__ __launch_bounds__(BLOCK, 4) void gating_kernel(
    const float* __restrict__ x,
    const __bf16* __restrict__ WH,
    const __bf16* __restrict__ WL,
    const float* __restrict__ b,
    float* __restrict__ out,
    int n_tokens)
{
    __shared__ f32x4 info[4 * TOK_PER_WAVE];   // per-wave {i1,i2,g1,g2} per token

    const int tid = threadIdx.x;
    const int w   = tid >> 6;          // wave in block
    const int l   = tid & 63;          // lane
    const int cl  = l & 15;            // token-in-tile (C/D col)
    const int rg  = (l >> 4) & 3;      // row/k group

    const int wtok0 = blockIdx.x * TOK_PER_BLOCK + w * TOK_PER_WAVE;

    const bf16x8* __restrict__ WHv = reinterpret_cast<const bf16x8*>(WH);
    const bf16x8* __restrict__ WLv = reinterpret_cast<const bf16x8*>(WL);

    // ---- accumulators init with bias: expert e = g*16 + rg*4 + r ----
    f32x4 acc[NTILE][4];               // [Ttile][Etile]
#pragma unroll
    for (int g = 0; g < 4; ++g) {
        const f32x4 bi = *reinterpret_cast<const f32x4*>(b + g * 16 + rg * 4);
#pragma unroll
        for (int t = 0; t < NTILE; ++t) acc[t][g] = bi;
    }

    // per-lane x row pointers (frag: tok = Tt*16 + cl, k = s*32 + rg*8 + i)
    const float* xrow[NTILE];
#pragma unroll
    for (int t = 0; t < NTILE; ++t) {
        int tk = wtok0 + t * 16 + cl;
        tk = tk < n_tokens ? tk : (n_tokens - 1);
        xrow[t] = x + (size_t)tk * D_MODEL + rg * 8;
    }

    f32x4 xa[NTILE][2], xb[NTILE][2];  // double-buffered fp32 x fragments
    bf16x8 wh[4], wl[4];               // single-buffered W fragments

#define LOADX(BUF, S)                                                         \
    _Pragma("unroll")                                                         \
    for (int t = 0; t < NTILE; ++t) {                                         \
        const float* p = xrow[t] + (S) * 32;                                  \
        BUF[t][0] = *reinterpret_cast<const f32x4*>(p);                       \
        BUF[t][1] = *reinterpret_cast<const f32x4*>(p + 4);                   \
    }
#define LOADW(S)                                                              \
    _Pragma("unroll")                                                         \
    for (int g = 0; g < 4; ++g) {                                             \
        wh[g] = WHv[((S) * 4 + g) * 64 + l];                                  \
        wl[g] = WLv[((S) * 4 + g) * 64 + l];                                  \
    }
#define PROC(XB)                                                              \
    _Pragma("unroll")                                                         \
    for (int t = 0; t < NTILE; ++t) {                                         \
        bf16x8 bh, bl;                                                        \
        _Pragma("unroll")                                                     \
        for (int i = 0; i < 8; ++i) {                                         \
            const float f = (i < 4) ? XB[t][0][i] : XB[t][1][i - 4];          \
            const __bf16 hh = (__bf16)f;                                      \
            bh[i] = hh;                                                       \
            bl[i] = (__bf16)(f - (float)hh);                                  \
        }                                                                     \
        _Pragma("unroll")                                                     \
        for (int g = 0; g < 4; ++g) {                                         \
            f32x4 c = acc[t][g];                                              \
            c = __builtin_amdgcn_mfma_f32_16x16x32_bf16(wh[g], bh, c, 0, 0, 0); \
            c = __builtin_amdgcn_mfma_f32_16x16x32_bf16(wh[g], bl, c, 0, 0, 0); \
            c = __builtin_amdgcn_mfma_f32_16x16x32_bf16(wl[g], bh, c, 0, 0, 0); \
            acc[t][g] = c;                                                    \
        }                                                                     \
    }

    LOADX(xa, 0);
    for (int s = 0; s < NSTEP; s += 2) {
        LOADW(s);                       // oldest in vmcnt queue
        LOADX(xb, s + 1);               // stays in flight across PROC's W-wait
        PROC(xa);
        LOADW(s + 1);
        if (s + 2 < NSTEP) { LOADX(xa, s + 2); }
        PROC(xb);
    }
#undef LOADX
#undef LOADW
#undef PROC

    // ---- top-2 + softmax per token (token t: lanes cl, cl+16, cl+32, cl+48) ----
    const int wbase = w * TOK_PER_WAVE;
#pragma unroll
    for (int t = 0; t < NTILE; ++t) {
        float m1 = -INFINITY, m2 = -INFINITY;
        int i1 = 0, i2 = 0;
#pragma unroll
        for (int g = 0; g < 4; ++g) {
#pragma unroll
            for (int r = 0; r < 4; ++r) {
                const float v = acc[t][g][r];
                const int e = g * 16 + rg * 4 + r;
                if (v > m1)      { m2 = m1; i2 = i1; m1 = v; i1 = e; }
                else if (v > m2) { m2 = v;  i2 = e; }
            }
        }
#pragma unroll
        for (int d = 16; d <= 32; d <<= 1) {
            const float om1 = __shfl_xor(m1, d, 64);
            const int   oi1 = __shfl_xor(i1, d, 64);
            const float om2 = __shfl_xor(m2, d, 64);
            const int   oi2 = __shfl_xor(i2, d, 64);
            const bool  sw  = om1 > m1;
            const float a1 = sw ? om1 : m1; const int ai1 = sw ? oi1 : i1;
            const float cc = sw ? m1  : om1; const int ci = sw ? i1  : oi1;
            const float dd = sw ? om2 : m2;  const int di = sw ? oi2 : i2;
            const bool  sw2 = dd > cc;
            m1 = a1; i1 = ai1;
            m2 = sw2 ? dd : cc; i2 = sw2 ? di : ci;
        }
        const float e2 = expf(m2 - m1);
        const float g1 = 1.0f / (1.0f + e2);
        const float g2 = e2 * g1;
        if (rg == 0) {
            f32x4 q;
            q[0] = __int_as_float(i1);
            q[1] = __int_as_float(i2);
            q[2] = g1;
            q[3] = g2;
            info[wbase + t * 16 + cl] = q;   // same-wave DS ordering; no barrier needed
        }
    }

    // ---- coalesced sparse scatter: 32 rows x 16 f32x4 per wave ----
    // fixed j: rows j*4 + rg (4 consecutive rows) x 16 lanes -> 1 KB contiguous
#pragma unroll
    for (int j = 0; j < TOK_PER_WAVE / 4; ++j) {
        const int row = j * 4 + rg;        // 0..31
        const f32x4 q = info[wbase + row];
        const int I1 = __float_as_int(q[0]);
        const int I2 = __float_as_int(q[1]);
        const float G1 = q[2], G2 = q[3];
        const int e0 = cl * 4;
        f32x4 o;
#pragma unroll
        for (int c = 0; c < 4; ++c) {
            const int e = e0 + c;
            o[c] = (e == I1) ? G1 : ((e == I2) ? G2 : 0.0f);
        }
        const int tokg = wtok0 + row;
        if (tokg < n_tokens) {
            reinterpret_cast<f32x4*>(out + (size_t)tokg * N_EXP)[cl] = o;
        }
    }
}

extern "C" void kernel_launch(void* const* d_in, const int* in_sizes, int n_in,
                              void* d_out, int out_size, void* d_ws, size_t ws_size,
                              hipStream_t stream) {
    const float* x = (const float*)d_in[0];
    const float* W = (const float*)d_in[1];
    const float* b = (const float*)d_in[2];
    float* out = (float*)d_out;

    const int n_tokens = in_sizes[0] / D_MODEL;             // 131072

    __bf16* WH = (__bf16*)d_ws;                             // 128 KB
    __bf16* WL = WH + (size_t)N_EXP * D_MODEL;              // 128 KB

    wprep_kernel<<<32, 256, 0, stream>>>(W, WH, WL);

    const int grid = (n_tokens + TOK_PER_BLOCK - 1) / TOK_PER_BLOCK;  // 1024
    gating_kernel<<<grid, BLOCK, 0, stream>>>(x, WH, WL, b, out, n_tokens);
}

// Round 3
// 725.927 us; speedup vs baseline: 1.0082x; 1.0082x over previous
//
#include <hip/hip_runtime.h>
#include <math.h>

// GatingFunc: logits = x @ W^T + b; top-2 -> softmax -> scatter to [N, E].
// N=131072, D=1024, E=64, K=2 (fp32 in/out).
//
// Round 6: coalescing fix. Rounds 4-5 loaded x fragments directly: 64 lanes x
// 16 B at 4-KB row stride = 64 uncoalesced 16-B requests per instruction.
// Round 5 doubled occupancy with ZERO gain -> bound by per-CU outstanding
// miss slots (~64 x 64-B sectors / 900 cy = ~2.8 TB/s chip-wide; measured
// 2.4 TB/s). Fix: block-level LDS staging of x with fully-coalesced 256-B
// row segments, transposed+XOR-swizzled LDS tile, fragments via ds_read_b128.
//  - block = 128 tokens, chunk = 2 K-steps (64 floats/row, 32 KB tile,
//    double-buffered = 64 KB LDS -> 2 blocks/CU, launch_bounds(256,2)).
//  - LDS layout byte(ch,row) = ch*2048 + ((row^(ch&7))<<4): write and read
//    both bank-balanced (8 bank-cycles inherent for b128, no extra conflict).
//  - W frags for BOTH sub-steps issued BEFORE the x-tile prefetch, so the
//    compiler's MFMA waits are vmcnt(16)/vmcnt(8) and the 32-KB x prefetch
//    stays in flight under the whole compute phase. One barrier per chunk.
//  - math unchanged from round 4/5 (split-bf16 3-pass MFMA, same K order ->
//    identical absmax): wave = 32 tok x 64 experts, mfma_f32_16x16x32_bf16,
//    C/D col=lane&15 (token), row=(lane>>4)*4+reg (expert) [HW-verified].
//  - epilogue unchanged: local top-2 + 2 shfl_xor merges, LDS redistribute,
//    coalesced f32x4 scatter.

#define D_MODEL 1024
#define N_EXP   64
#define NSTEP   32          // K-steps of 32 (MFMA K)
#define BLOCK   256
#define TOK_PER_WAVE  32
#define TOK_PER_BLOCK 128
#define NTILE   2           // 16-token C tiles per wave
#define NCHUNK  16          // chunks of 2 K-steps
#define CH_BYTES 2048       // 128 rows * 16 B per chunk-slot

typedef float  f32x4 __attribute__((ext_vector_type(4)));
typedef __bf16 bf16x8 __attribute__((ext_vector_type(8)));

// ---- prep: pack W [64][1024] fp32 -> bf16 hi/lo A-fragments ----
// chunk c = (s*4 + g)*64 + l holds W[e = g*16 + (l&15)][k = s*32 + (l>>4)*8 .. +7]
__global__ __launch_bounds__(256) void wprep_kernel(
    const float* __restrict__ W, __bf16* __restrict__ WH, __bf16* __restrict__ WL)
{
    const int tid = blockIdx.x * 256 + threadIdx.x;   // 0..8191
    const int s = tid >> 8;
    const int g = (tid >> 6) & 3;
    const int l = tid & 63;
    const int e  = g * 16 + (l & 15);
    const int k0 = s * 32 + ((l >> 4) & 3) * 8;
    const float* __restrict__ src = W + (size_t)e * D_MODEL + k0;
    bf16x8 h, lo;
#pragma unroll
    for (int i = 0; i < 8; ++i) {
        const float f = src[i];
        const __bf16 hh = (__bf16)f;
        h[i]  = hh;
        lo[i] = (__bf16)(f - (float)hh);
    }
    reinterpret_cast<bf16x8*>(WH)[tid] = h;
    reinterpret_cast<bf16x8*>(WL)[tid] = lo;
}

__global__ __launch_bounds__(BLOCK, 2) void gating_kernel(
    const float* __restrict__ x,
    const __bf16* __restrict__ WH,
    const __bf16* __restrict__ WL,
    const float* __restrict__ b,
    float* __restrict__ out,
    int n_tokens)
{
    __shared__ char  xs[2][16 * CH_BYTES];     // 64 KB x tile, double-buffered
    __shared__ f32x4 info[4 * TOK_PER_WAVE];   // per-wave {i1,i2,g1,g2} per token

    const int tid = threadIdx.x;
    const int w   = tid >> 6;          // wave in block
    const int l   = tid & 63;          // lane
    const int cl  = l & 15;            // token-in-tile (C/D col)
    const int rg  = (l >> 4) & 3;      // row/k group

    const int btok  = blockIdx.x * TOK_PER_BLOCK;
    const int wtok0 = btok + w * TOK_PER_WAVE;

    const bf16x8* __restrict__ WHv = reinterpret_cast<const bf16x8*>(WH);
    const bf16x8* __restrict__ WLv = reinterpret_cast<const bf16x8*>(WL);

    // ---- accumulators init with bias: expert e = g*16 + rg*4 + r ----
    f32x4 acc[NTILE][4];               // [Ttile][Etile]
#pragma unroll
    for (int g = 0; g < 4; ++g) {
        const f32x4 bi = *reinterpret_cast<const f32x4*>(b + g * 16 + rg * 4);
#pragma unroll
        for (int t = 0; t < NTILE; ++t) acc[t][g] = bi;
    }

    f32x4 U[8];                        // staged x chunk (reg)
    bf16x8 wha[4], wla[4], whb[4], wlb[4];   // W frags for both sub-steps

    // staging: element g = i*256+tid -> row = g>>4, ch = g&15.
    // global: 16 consecutive lanes read 256 B contiguous of one token row.
#define STAGE_LOAD(C)                                                         \
    _Pragma("unroll")                                                         \
    for (int i = 0; i < 8; ++i) {                                             \
        const int gg = i * BLOCK + tid;                                       \
        const int srow = gg >> 4, sch = gg & 15;                              \
        int tk = btok + srow; tk = tk < n_tokens ? tk : (n_tokens - 1);       \
        U[i] = *reinterpret_cast<const f32x4*>(                               \
            x + (size_t)tk * D_MODEL + (C) * 64 + sch * 4);                   \
    }
#define STAGE_WRITE(BUF)                                                      \
    _Pragma("unroll")                                                         \
    for (int i = 0; i < 8; ++i) {                                             \
        const int gg = i * BLOCK + tid;                                       \
        const int srow = gg >> 4, sch = gg & 15;                              \
        *reinterpret_cast<f32x4*>(                                            \
            xs[BUF] + sch * CH_BYTES + ((srow ^ (sch & 7)) << 4)) = U[i];     \
    }
#define LOADW(WH_, WL_, S)                                                    \
    _Pragma("unroll")                                                         \
    for (int g = 0; g < 4; ++g) {                                             \
        WH_[g] = WHv[((S) * 4 + g) * 64 + l];                                 \
        WL_[g] = WLv[((S) * 4 + g) * 64 + l];                                 \
    }
    // sub-step Q of chunk in xs[BUF]: frag (t): row = w*32+t*16+cl,
    // halves ch = Q*8 + rg*2 + {0,1}
#define PROCQ(BUF, Q, WH_, WL_)                                               \
    _Pragma("unroll")                                                         \
    for (int t = 0; t < NTILE; ++t) {                                         \
        const int row = w * TOK_PER_WAVE + t * 16 + cl;                       \
        bf16x8 bh, bl;                                                        \
        _Pragma("unroll")                                                     \
        for (int hf = 0; hf < 2; ++hf) {                                      \
            const int ch = (Q) * 8 + rg * 2 + hf;                             \
            const f32x4 xf = *reinterpret_cast<const f32x4*>(                 \
                xs[BUF] + ch * CH_BYTES + ((row ^ (ch & 7)) << 4));           \
            _Pragma("unroll")                                                 \
            for (int ii = 0; ii < 4; ++ii) {                                  \
                const float f = xf[ii];                                       \
                const __bf16 hv = (__bf16)f;                                  \
                bh[hf * 4 + ii] = hv;                                         \
                bl[hf * 4 + ii] = (__bf16)(f - (float)hv);                    \
            }                                                                 \
        }                                                                     \
        _Pragma("unroll")                                                     \
        for (int g = 0; g < 4; ++g) {                                         \
            f32x4 c = acc[t][g];                                              \
            c = __builtin_amdgcn_mfma_f32_16x16x32_bf16(WH_[g], bh, c, 0, 0, 0); \
            c = __builtin_amdgcn_mfma_f32_16x16x32_bf16(WH_[g], bl, c, 0, 0, 0); \
            c = __builtin_amdgcn_mfma_f32_16x16x32_bf16(WL_[g], bh, c, 0, 0, 0); \
            acc[t][g] = c;                                                    \
        }                                                                     \
    }

    // ---- prologue: stage chunk 0 ----
    STAGE_LOAD(0);
    STAGE_WRITE(0);                    // vmcnt wait inserted by compiler
    __syncthreads();

    // ---- main loop: one barrier per chunk, x prefetch in flight across compute ----
    for (int c = 0; c < NCHUNK; ++c) {
        const int cur = c & 1;
        // W first (oldest in vmcnt queue), then x prefetch (newest) -> MFMA
        // W-waits are vmcnt(16)/vmcnt(8), x-tile loads stay in flight.
        LOADW(wha, wla, 2 * c);
        LOADW(whb, wlb, 2 * c + 1);
        if (c + 1 < NCHUNK) STAGE_LOAD(c + 1);
        PROCQ(cur, 0, wha, wla);
        PROCQ(cur, 1, whb, wlb);
        if (c + 1 < NCHUNK) {
            STAGE_WRITE(cur ^ 1);      // other buffer; prev-iter barrier protects
            __syncthreads();           // publish
        }
    }
#undef STAGE_LOAD
#undef STAGE_WRITE
#undef LOADW
#undef PROCQ

    // ---- top-2 + softmax per token (token t: lanes cl, cl+16, cl+32, cl+48) ----
    const int wbase = w * TOK_PER_WAVE;
#pragma unroll
    for (int t = 0; t < NTILE; ++t) {
        float m1 = -INFINITY, m2 = -INFINITY;
        int i1 = 0, i2 = 0;
#pragma unroll
        for (int g = 0; g < 4; ++g) {
#pragma unroll
            for (int r = 0; r < 4; ++r) {
                const float v = acc[t][g][r];
                const int e = g * 16 + rg * 4 + r;
                if (v > m1)      { m2 = m1; i2 = i1; m1 = v; i1 = e; }
                else if (v > m2) { m2 = v;  i2 = e; }
            }
        }
#pragma unroll
        for (int d = 16; d <= 32; d <<= 1) {
            const float om1 = __shfl_xor(m1, d, 64);
            const int   oi1 = __shfl_xor(i1, d, 64);
            const float om2 = __shfl_xor(m2, d, 64);
            const int   oi2 = __shfl_xor(i2, d, 64);
            const bool  sw  = om1 > m1;
            const float a1 = sw ? om1 : m1; const int ai1 = sw ? oi1 : i1;
            const float cc = sw ? m1  : om1; const int ci = sw ? i1  : oi1;
            const float dd = sw ? om2 : m2;  const int di = sw ? oi2 : i2;
            const bool  sw2 = dd > cc;
            m1 = a1; i1 = ai1;
            m2 = sw2 ? dd : cc; i2 = sw2 ? di : ci;
        }
        const float e2 = expf(m2 - m1);
        const float g1 = 1.0f / (1.0f + e2);
        const float g2 = e2 * g1;
        if (rg == 0) {
            f32x4 q;
            q[0] = __int_as_float(i1);
            q[1] = __int_as_float(i2);
            q[2] = g1;
            q[3] = g2;
            info[wbase + t * 16 + cl] = q;   // same-wave DS ordering; no barrier needed
        }
    }

    // ---- coalesced sparse scatter: 32 rows x 16 f32x4 per wave ----
#pragma unroll
    for (int j = 0; j < TOK_PER_WAVE / 4; ++j) {
        const int row = j * 4 + rg;        // 0..31
        const f32x4 q = info[wbase + row];
        const int I1 = __float_as_int(q[0]);
        const int I2 = __float_as_int(q[1]);
        const float G1 = q[2], G2 = q[3];
        const int e0 = cl * 4;
        f32x4 o;
#pragma unroll
        for (int ccx = 0; ccx < 4; ++ccx) {
            const int e = e0 + ccx;
            o[ccx] = (e == I1) ? G1 : ((e == I2) ? G2 : 0.0f);
        }
        const int tokg = wtok0 + row;
        if (tokg < n_tokens) {
            reinterpret_cast<f32x4*>(out + (size_t)tokg * N_EXP)[cl] = o;
        }
    }
}

extern "C" void kernel_launch(void* const* d_in, const int* in_sizes, int n_in,
                              void* d_out, int out_size, void* d_ws, size_t ws_size,
                              hipStream_t stream) {
    const float* x = (const float*)d_in[0];
    const float* W = (const float*)d_in[1];
    const float* b = (const float*)d_in[2];
    float* out = (float*)d_out;

    const int n_tokens = in_sizes[0] / D_MODEL;             // 131072

    __bf16* WH = (__bf16*)d_ws;                             // 128 KB
    __bf16* WL = WH + (size_t)N_EXP * D_MODEL;              // 128 KB

    wprep_kernel<<<32, 256, 0, stream>>>(W, WH, WL);

    const int grid = (n_tokens + TOK_PER_BLOCK - 1) / TOK_PER_BLOCK;  // 1024
    gating_kernel<<<grid, BLOCK, 0, stream>>>(x, WH, WL, b, out, n_tokens);
}